// Round 1
// baseline (170.166 us; speedup 1.0000x reference)
//
#include <hip/hip_runtime.h>
#include <hip/hip_bf16.h>

#define NN 4096
#define DD 256
#define OO 256

typedef __attribute__((ext_vector_type(4))) float f32x4;
typedef __attribute__((ext_vector_type(8))) short bf16x8;
typedef __attribute__((ext_vector_type(4))) unsigned int u32x4;

__device__ __forceinline__ short f2bfs(float f) {
    __hip_bfloat16 h = __float2bfloat16(f);
    short s;
    __builtin_memcpy(&s, &h, 2);
    return s;
}

// K1: XWT[o][m] = sum_k X[m][k] * W[k][o], output bf16, layout [OO][NN] row-major.
// grid 256 blocks (m-tiles of 16), 256 threads (thread t -> o = t).
__global__ __launch_bounds__(256) void k1_xwt(
    const float* __restrict__ X, const float* __restrict__ W,
    unsigned short* __restrict__ XWT)
{
    __shared__ float xs[16][DD];
    const int t = threadIdx.x;
    const int m0 = blockIdx.x * 16;

    #pragma unroll
    for (int i = 0; i < 16; ++i)
        xs[i][t] = X[(size_t)(m0 + i) * DD + t];
    __syncthreads();

    float acc[16];
    #pragma unroll
    for (int m = 0; m < 16; ++m) acc[m] = 0.f;

    for (int k0 = 0; k0 < DD; k0 += 4) {
        float w0 = W[(size_t)(k0 + 0) * OO + t];
        float w1 = W[(size_t)(k0 + 1) * OO + t];
        float w2 = W[(size_t)(k0 + 2) * OO + t];
        float w3 = W[(size_t)(k0 + 3) * OO + t];
        #pragma unroll
        for (int m = 0; m < 16; ++m) {
            const f32x4 xv = *reinterpret_cast<const f32x4*>(&xs[m][k0]);
            acc[m] = fmaf(xv[0], w0, acc[m]);
            acc[m] = fmaf(xv[1], w1, acc[m]);
            acc[m] = fmaf(xv[2], w2, acc[m]);
            acc[m] = fmaf(xv[3], w3, acc[m]);
        }
    }

    // pack 16 bf16 (XWT[t][m0..m0+15]) into two 16B stores
    unsigned int p[8];
    #pragma unroll
    for (int i = 0; i < 8; ++i) {
        unsigned lo = (unsigned short)f2bfs(acc[2 * i]);
        unsigned hi = (unsigned short)f2bfs(acc[2 * i + 1]);
        p[i] = lo | (hi << 16);
    }
    u32x4* dst = reinterpret_cast<u32x4*>(XWT + (size_t)t * NN + m0);
    dst[0] = (u32x4){p[0], p[1], p[2], p[3]};
    dst[1] = (u32x4){p[4], p[5], p[6], p[7]};
}

// K2: fused  out[y,o] = sum_n Beta[n,y]*XW[n,o]  +  (sum_n Beta[n,y]*adj[n,y,:]) @ Wa + bias
// grid 256 blocks (y-tiles of 16), 512 threads = 8 waves; wave w owns o in [32w, 32w+32).
__global__ __launch_bounds__(512) void k2_fused(
    const float* __restrict__ Beta, const unsigned short* __restrict__ XWT,
    const float* __restrict__ Adj, const float* __restrict__ W,
    const float* __restrict__ bias, float* __restrict__ Out)
{
    const int t = threadIdx.x;
    const int lane = t & 63;
    const int wave = t >> 6;      // 0..7
    const int g16 = lane >> 4;    // 0..3
    const int r16 = lane & 15;
    const int y0 = blockIdx.x * 16;

    // GEMM pointers: A = Beta^T (k = n contiguous per lane by convention), B = XWT rows
    const float* bA = Beta + (size_t)(8 * g16) * NN + (y0 + r16);
    const unsigned short* xw0 = XWT + (size_t)(32 * wave + r16) * NN + 8 * g16;
    const unsigned short* xw1 = xw0 + (size_t)16 * NN;

    // adjacency: thread handles (y = t&15, n-offset g = t>>4) within each 32-n step
    const int ga = t >> 4;        // 0..31
    const int ya = t & 15;
    const float* bS = Beta + (size_t)ga * NN + (y0 + ya);
    const float* aS = Adj + ((size_t)ga * NN + (y0 + ya)) * 3;

    f32x4 d0 = {0.f, 0.f, 0.f, 0.f};
    f32x4 d1 = {0.f, 0.f, 0.f, 0.f};
    float agg0 = 0.f, agg1 = 0.f, agg2 = 0.f;

    for (int n0 = 0; n0 < NN; n0 += 32) {
        // A fragment: Beta[n0 + 8*g16 + j][y0 + r16], j = 0..7
        float a0 = bA[0 * NN];
        float a1 = bA[1 * NN];
        float a2 = bA[2 * NN];
        float a3 = bA[3 * NN];
        float a4 = bA[4 * NN];
        float a5 = bA[5 * NN];
        float a6 = bA[6 * NN];
        float a7 = bA[7 * NN];
        bf16x8 av;
        av[0] = f2bfs(a0); av[1] = f2bfs(a1); av[2] = f2bfs(a2); av[3] = f2bfs(a3);
        av[4] = f2bfs(a4); av[5] = f2bfs(a5); av[6] = f2bfs(a6); av[7] = f2bfs(a7);

        bf16x8 b0 = *reinterpret_cast<const bf16x8*>(xw0);
        bf16x8 b1 = *reinterpret_cast<const bf16x8*>(xw1);

        d0 = __builtin_amdgcn_mfma_f32_16x16x32_bf16(av, b0, d0, 0, 0, 0);
        d1 = __builtin_amdgcn_mfma_f32_16x16x32_bf16(av, b1, d1, 0, 0, 0);

        // adjacency partial: one (n, y) row, 3 channels
        float bv = *bS;
        agg0 = fmaf(bv, aS[0], agg0);
        agg1 = fmaf(bv, aS[1], agg1);
        agg2 = fmaf(bv, aS[2], agg2);

        bA += (size_t)32 * NN;
        xw0 += 32;
        xw1 += 32;
        bS += (size_t)32 * NN;
        aS += (size_t)32 * NN * 3;
    }

    // reduce agg over the 32 n-groups
    __shared__ float lagg[32][16][3];
    __shared__ float fin[16][3];
    lagg[ga][ya][0] = agg0;
    lagg[ga][ya][1] = agg1;
    lagg[ga][ya][2] = agg2;
    __syncthreads();
    if (t < 48) {
        const int yy = t / 3, cc = t % 3;
        float s = 0.f;
        #pragma unroll
        for (int g = 0; g < 32; ++g) s += lagg[g][yy][cc];
        fin[yy][cc] = s;
    }
    __syncthreads();

    // epilogue: out = D + agg @ Wa + bias
    #pragma unroll
    for (int f = 0; f < 2; ++f) {
        const int o = 32 * wave + 16 * f + r16;
        const float wa0 = W[(size_t)(DD + 0) * OO + o];
        const float wa1 = W[(size_t)(DD + 1) * OO + o];
        const float wa2 = W[(size_t)(DD + 2) * OO + o];
        const float bo  = bias[o];
        const f32x4 dd = f ? d1 : d0;
        #pragma unroll
        for (int r = 0; r < 4; ++r) {
            const int yl = 4 * g16 + r;
            const float add = fin[yl][0] * wa0 + fin[yl][1] * wa1 + fin[yl][2] * wa2 + bo;
            Out[(size_t)(y0 + yl) * OO + o] = dd[r] + add;
        }
    }
}

extern "C" void kernel_launch(void* const* d_in, const int* in_sizes, int n_in,
                              void* d_out, int out_size, void* d_ws, size_t ws_size,
                              hipStream_t stream) {
    (void)in_sizes; (void)n_in; (void)out_size; (void)ws_size;
    const float* adj  = (const float*)d_in[0];  // (N, N, C)
    const float* X    = (const float*)d_in[1];  // (N, D)
    const float* Beta = (const float*)d_in[2];  // (N, N)
    const float* W    = (const float*)d_in[3];  // (D+C, O)
    const float* bias = (const float*)d_in[4];  // (O)
    float* out = (float*)d_out;                 // (N, O) fp32

    unsigned short* XWT = (unsigned short*)d_ws;  // bf16 [OO][NN], 2 MB

    k1_xwt<<<dim3(NN / 16), dim3(256), 0, stream>>>(X, W, XWT);
    k2_fused<<<dim3(NN / 16), dim3(512), 0, stream>>>(Beta, XWT, adj, W, bias, out);
}